// Round 7
// baseline (28943.378 us; speedup 1.0000x reference)
//
#include <hip/hip_runtime.h>
#include <stdint.h>

// ---------------- constants ----------------
#define T_STEPS 1000
#define BATCHN  4096
#define SDIM    128
#define ADIM    32
#define HID     256
#define TDIM    16
#define KPH     264   // ushort stride for hidden activation buffers (132 dwords)
#define KPX     40    // ushort stride for x buffer

typedef __attribute__((ext_vector_type(8))) short short8;   // 8 bf16 (4 VGPRs)
typedef __attribute__((ext_vector_type(4))) float f32x4;    // MFMA accumulator

union BPack { short8 s8; uint32_t u[4]; };

// ---------------- bf16 helpers ----------------
__device__ __forceinline__ unsigned short f2bf(float f) {   // RNE
  uint32_t u = __float_as_uint(f);
  u = u + 0x7FFFu + ((u >> 16) & 1u);
  return (unsigned short)(u >> 16);
}
__device__ __forceinline__ float bf2f(unsigned short h) {
  return __uint_as_float(((uint32_t)h) << 16);
}

// split f32 weight into (hi RTZ-bf16, lo bf16 of exact residual), packed pairs
__device__ __forceinline__ void pack_split(const uint32_t u[8], short8& h, short8& l) {
  BPack hh, ll;
#pragma unroll
  for (int q = 0; q < 4; ++q) {
    uint32_t u0 = u[2 * q], u1 = u[2 * q + 1];
    hh.u[q] = (u0 >> 16) | (u1 & 0xFFFF0000u);
    float f0 = __uint_as_float(u0) - __uint_as_float(u0 & 0xFFFF0000u);  // exact
    float f1 = __uint_as_float(u1) - __uint_as_float(u1 & 0xFFFF0000u);  // exact
    ll.u[q] = (__float_as_uint(f0) >> 16) | (__float_as_uint(f1) & 0xFFFF0000u);
  }
  h = hh.s8; l = ll.s8;
}

// ---------------- threefry2x32 (exact JAX semantics) ----------------
__device__ __forceinline__ uint32_t rotl32(uint32_t v, int d) {
  return (v << d) | (v >> (32 - d));
}
__device__ __forceinline__ void threefry2x32(uint32_t k0, uint32_t k1,
                                             uint32_t x0, uint32_t x1,
                                             uint32_t& o0, uint32_t& o1) {
  uint32_t ks0 = k0, ks1 = k1, ks2 = k0 ^ k1 ^ 0x1BD11BDAu;
  x0 += ks0; x1 += ks1;
#define TF_ROUND(r) { x0 += x1; x1 = rotl32(x1, (r)); x1 ^= x0; }
  TF_ROUND(13) TF_ROUND(15) TF_ROUND(26) TF_ROUND(6)
  x0 += ks1; x1 += ks2 + 1u;
  TF_ROUND(17) TF_ROUND(29) TF_ROUND(16) TF_ROUND(24)
  x0 += ks2; x1 += ks0 + 2u;
  TF_ROUND(13) TF_ROUND(15) TF_ROUND(26) TF_ROUND(6)
  x0 += ks0; x1 += ks1 + 3u;
  TF_ROUND(17) TF_ROUND(29) TF_ROUND(16) TF_ROUND(24)
  x0 += ks1; x1 += ks2 + 4u;
  TF_ROUND(13) TF_ROUND(15) TF_ROUND(26) TF_ROUND(6)
  x0 += ks2; x1 += ks0 + 5u;
#undef TF_ROUND
  o0 = x0; o1 = x1;
}
// JAX partitionable threefry random_bits (bit_width=32): XOR combine of both words.
__device__ __forceinline__ uint32_t random_bits32_partitionable(uint32_t k0, uint32_t k1,
                                                               uint32_t j) {
  uint32_t o0, o1;
  threefry2x32(k0, k1, 0u, j, o0, o1);
  return o0 ^ o1;
}

// ---------------- XLA ErfInv (f32 Giles polynomial) ----------------
__device__ __forceinline__ float erfinv_f32(float x) {
  float w = -log1pf(-(x * x));
  float p;
  if (w < 5.0f) {
    w = w - 2.5f;
    p = 2.81022636e-08f;
    p = fmaf(p, w, 3.43273939e-07f);
    p = fmaf(p, w, -3.5233877e-06f);
    p = fmaf(p, w, -4.39150654e-06f);
    p = fmaf(p, w, 0.00021858087f);
    p = fmaf(p, w, -0.00125372503f);
    p = fmaf(p, w, -0.00417768164f);
    p = fmaf(p, w, 0.246640727f);
    p = fmaf(p, w, 1.50140941f);
  } else {
    w = sqrtf(w) - 3.0f;
    p = -0.000200214257f;
    p = fmaf(p, w, 0.000100950558f);
    p = fmaf(p, w, 0.00134934322f);
    p = fmaf(p, w, -0.00367342844f);
    p = fmaf(p, w, 0.00573950773f);
    p = fmaf(p, w, -0.0076224613f);
    p = fmaf(p, w, 0.00943887047f);
    p = fmaf(p, w, 1.00167406f);
    p = fmaf(p, w, 2.83297682f);
  }
  return p * x;
}
__device__ __forceinline__ float bits_to_normal(uint32_t bits) {
  float f = __uint_as_float((bits >> 9) | 0x3F800000u) - 1.0f;   // [0,1)
  float u = f * 2.0f + (-0.99999994f);
  u = fmaxf(-0.99999994f, u);
  return 1.41421356237309515f * erfinv_f32(u);   // sqrt(2) as f32
}

// mish(x) = x * t/(t+2), t = e^x (e^x + 2); clamp arg (identical in f32 for x>=20)
__device__ __forceinline__ float mish_f(float x) {
  float e = expf(fminf(x, 20.0f));
  float t = fmaf(e, e, 2.0f * e);
  return x * (t / (t + 2.0f));
}

// ---------------- precompute: tf_all[1000][16], coefs[5][1000], keys[1000][2] --------
__global__ __launch_bounds__(64)
void precompute_kernel(const float* __restrict__ w_t1, const float* __restrict__ b_t1,
                       const float* __restrict__ w_t2, const float* __restrict__ b_t2,
                       float* __restrict__ tf_all, float* __restrict__ coefs,
                       uint32_t* __restrict__ keys) {
  const int i = blockIdx.x;
  const int j = threadIdx.x;
  const float tv = (float)i;
  __shared__ float hid[32];
  const float CF = (float)(-1.3157629102823120);  // -log(10000)/7
  if (j < 32) {
    float acc = b_t1[j];
#pragma unroll
    for (int k = 0; k < 16; ++k) {
      int kf = (k < 8) ? k : (k - 8);
      float fr = expf((float)kf * CF);
      float ang = tv * fr;
      float te = (k < 8) ? sinf(ang) : cosf(ang);
      acc = fmaf(te, w_t1[k * 32 + j], acc);
    }
    hid[j] = mish_f(acc);
  }
  __syncthreads();
  if (j < 16) {
    float acc = b_t2[j];
#pragma unroll
    for (int k2 = 0; k2 < 32; ++k2) acc = fmaf(hid[k2], w_t2[k2 * 16 + j], acc);
    tf_all[i * TDIM + j] = acc;
  }
  if (j == 0) {
    double t = (double)(i + 1);
    double ac  = exp(-0.1 * t / 1000.0 - 4.95 * t * t / 1.0e6);
    double acp = (i == 0) ? 1.0
        : exp(-0.1 * (t - 1.0) / 1000.0 - 4.95 * (t - 1.0) * (t - 1.0) / 1.0e6);
    double alpha = exp(-0.1 / 1000.0 - 4.95 * (2.0 * t - 1.0) / 1.0e6);
    double beta = 1.0 - alpha;
    double sr   = sqrt(1.0 / ac);
    double srm1 = sqrt(1.0 / ac - 1.0);
    double c1 = beta * sqrt(acp) / (1.0 - ac);
    double c2 = (1.0 - acp) * sqrt(alpha) / (1.0 - ac);
    double pv = beta * (1.0 - acp) / (1.0 - ac);
    double lv = log(fmax(pv, 1.0e-20));
    coefs[0 * T_STEPS + i] = (float)sr;
    coefs[1 * T_STEPS + i] = (float)srm1;
    coefs[2 * T_STEPS + i] = (float)c1;
    coefs[3 * T_STEPS + i] = (float)c2;
    float lvf = (float)lv;
    coefs[4 * T_STEPS + i] = expf(0.5f * lvf);
    uint32_t o0, o1;
    threefry2x32(0u, 1u, 0u, (uint32_t)i, o0, o1);
    keys[2 * i]     = o0;
    keys[2 * i + 1] = o1;
  }
}

// ------- tfc[t][n] = b0[n] + sum_k tf[t][k] * w0[(32+k)*256+n]  (fp32) -------------
__global__ __launch_bounds__(256)
void tfc_kernel(const float* __restrict__ tf_all, const float* __restrict__ w0,
                const float* __restrict__ b0, float* __restrict__ tfc) {
  const int t = blockIdx.x, n = threadIdx.x;
  __shared__ float tf[TDIM];
  if (n < TDIM) tf[n] = tf_all[t * TDIM + n];
  __syncthreads();
  float acc = b0[n];
#pragma unroll
  for (int k = 0; k < TDIM; ++k) acc = fmaf(tf[k], w0[(ADIM + k) * HID + n], acc);
  tfc[t * HID + n] = acc;
}

// ---------------- dense layer via split-bf16 MFMA, weights f32 from d_in ----------
// MODE 0: L0 (epilogue adds sc_state + tfc, mish). 1: hidden (bias+mish). 2: final (bias->eps)
template <int NKT, int MODE, bool DUAL>
__device__ __forceinline__ void dense_layer(
    const float* __restrict__ W, int N,
    const unsigned short* __restrict__ srcH, const unsigned short* __restrict__ srcL,
    int sstride, unsigned short* __restrict__ dstH, unsigned short* __restrict__ dstL,
    int dstride, float bA, float bB,
    const float* __restrict__ sc, const float* __restrict__ tfc_t,
    float* __restrict__ eps,
    int lrow, int quad, int nt0, int nt1) {
  f32x4 acc0 = {0.f, 0.f, 0.f, 0.f}, acc1 = {0.f, 0.f, 0.f, 0.f};
  const int n0 = nt0 * 16 + lrow, n1 = nt1 * 16 + lrow;
  uint32_t cu0[8], cu1[8], nu0[8], nu1[8];
  const float* p0 = W + quad * 8 * N + n0;
  const float* p1 = W + quad * 8 * N + n1;
#pragma unroll
  for (int j = 0; j < 8; ++j) {
    cu0[j] = __float_as_uint(p0[j * N]);
    if (DUAL) cu1[j] = __float_as_uint(p1[j * N]);
  }
  const unsigned short* aHb = srcH + lrow * sstride + quad * 8;
  const unsigned short* aLb = srcL + lrow * sstride + quad * 8;
#pragma unroll
  for (int kt = 0; kt < NKT; ++kt) {
    if (kt + 1 < NKT) {
      const float* q0 = p0 + (kt + 1) * 32 * N;
      const float* q1 = p1 + (kt + 1) * 32 * N;
#pragma unroll
      for (int j = 0; j < 8; ++j) {
        nu0[j] = __float_as_uint(q0[j * N]);
        if (DUAL) nu1[j] = __float_as_uint(q1[j * N]);
      }
    }
    short8 bh0, bl0, bh1, bl1;
    pack_split(cu0, bh0, bl0);
    if (DUAL) pack_split(cu1, bh1, bl1);
    short8 ah = *reinterpret_cast<const short8*>(aHb + kt * 32);
    short8 al = *reinterpret_cast<const short8*>(aLb + kt * 32);
    acc0 = __builtin_amdgcn_mfma_f32_16x16x32_bf16(ah, bh0, acc0, 0, 0, 0);
    if (DUAL) acc1 = __builtin_amdgcn_mfma_f32_16x16x32_bf16(ah, bh1, acc1, 0, 0, 0);
    acc0 = __builtin_amdgcn_mfma_f32_16x16x32_bf16(al, bh0, acc0, 0, 0, 0);
    if (DUAL) acc1 = __builtin_amdgcn_mfma_f32_16x16x32_bf16(al, bh1, acc1, 0, 0, 0);
    acc0 = __builtin_amdgcn_mfma_f32_16x16x32_bf16(ah, bl0, acc0, 0, 0, 0);
    if (DUAL) acc1 = __builtin_amdgcn_mfma_f32_16x16x32_bf16(ah, bl1, acc1, 0, 0, 0);
#pragma unroll
    for (int j = 0; j < 8; ++j) { cu0[j] = nu0[j]; if (DUAL) cu1[j] = nu1[j]; }
  }
  // epilogue: C/D layout col = lane&15, row = quad*4 + reg
#pragma unroll
  for (int reg = 0; reg < 4; ++reg) {
    int orow = quad * 4 + reg;
    if (MODE == 2) {
      eps[orow * ADIM + n0] = acc0[reg] + bA;
    } else {
      float v0, v1;
      if (MODE == 0) {
        v0 = mish_f(acc0[reg] + sc[orow * HID + n0] + tfc_t[n0]);
        v1 = mish_f(acc1[reg] + sc[orow * HID + n1] + tfc_t[n1]);
      } else {
        v0 = mish_f(acc0[reg] + bA);
        v1 = mish_f(acc1[reg] + bB);
      }
      unsigned short h0 = f2bf(v0), h1 = f2bf(v1);
      dstH[orow * dstride + n0] = h0;
      dstL[orow * dstride + n0] = f2bf(v0 - bf2f(h0));
      dstH[orow * dstride + n1] = h1;
      dstL[orow * dstride + n1] = f2bf(v1 - bf2f(h1));
    }
  }
}

// ---------------- persistent main kernel: 16 rows/block, weights from d_in --------
__global__ __launch_bounds__(512)
void diffusion_main(const float* __restrict__ state, const float* __restrict__ x_init,
                    const float* __restrict__ w0, const float* __restrict__ b1,
                    const float* __restrict__ b2, const float* __restrict__ bf,
                    const float* __restrict__ w1, const float* __restrict__ w2,
                    const float* __restrict__ wf,
                    const float* __restrict__ tfc, const float* __restrict__ coefs,
                    const uint32_t* __restrict__ keys, float* __restrict__ out) {
  // static LDS carve (56832 B total)
  __shared__ __align__(16) unsigned short Ph[16 * KPH], Pl[16 * KPH];
  __shared__ __align__(16) unsigned short Qh[16 * KPH], Ql[16 * KPH];
  __shared__ __align__(16) unsigned short A0h[16 * KPX], A0l[16 * KPX];
  __shared__ __align__(16) float sc[16 * HID];      // fp32 state-contrib to L0
  __shared__ float s_eps[16 * ADIM];
  __shared__ float s_x[16 * ADIM];

  const int tid = threadIdx.x;          // 0..511
  const int base = blockIdx.x * 8;
  const int l = tid & 63;
  const int w = tid >> 6;               // wave 0..7
  const int lrow = l & 15;
  const int quad = l >> 4;
  const int nt0 = 2 * w, nt1 = 2 * w + 1;

  // ---- init x ----
  {
    int r = tid >> 5, d = tid & 31;
    int grow = (r < 8) ? (base + r) : (2048 + base + r - 8);
    float v = x_init[grow * ADIM + d];
    s_x[r * ADIM + d] = v;
    unsigned short h = f2bf(v);
    A0h[r * KPX + d] = h; A0l[r * KPX + d] = f2bf(v - bf2f(h));
  }
  // ---- stage state f32 into Ph region (transient), compute sc in fp32 ----
  float* stateF = reinterpret_cast<float*>(Ph);    // 16*128 f32 = 8192 B <= Ph
  for (int idx = tid; idx < 16 * SDIM; idx += 512) {
    int r = idx >> 7, k = idx & 127;
    int grow = (r < 8) ? (base + r) : (2048 + base + r - 8);
    stateF[r * SDIM + k] = state[grow * SDIM + k];
  }
  __syncthreads();
  {
    int r = tid >> 5, nb = (tid & 31) * 8;
    float acc[8];
#pragma unroll
    for (int j = 0; j < 8; ++j) acc[j] = 0.0f;
    for (int k = 0; k < SDIM; ++k) {
      float s = stateF[r * SDIM + k];
      const float* wr = w0 + (ADIM + TDIM + k) * HID + nb;
      float4 wa = *reinterpret_cast<const float4*>(wr);
      float4 wb = *reinterpret_cast<const float4*>(wr + 4);
      acc[0] = fmaf(s, wa.x, acc[0]); acc[1] = fmaf(s, wa.y, acc[1]);
      acc[2] = fmaf(s, wa.z, acc[2]); acc[3] = fmaf(s, wa.w, acc[3]);
      acc[4] = fmaf(s, wb.x, acc[4]); acc[5] = fmaf(s, wb.y, acc[5]);
      acc[6] = fmaf(s, wb.z, acc[6]); acc[7] = fmaf(s, wb.w, acc[7]);
    }
    __syncthreads();   // done reading stateF before anything overwrites Ph
#pragma unroll
    for (int j = 0; j < 8; ++j) sc[r * HID + nb + j] = acc[j];
  }

  // per-lane biases
  const float b1A = b1[nt0 * 16 + lrow], b1B = b1[nt1 * 16 + lrow];
  const float b2A = b2[nt0 * 16 + lrow], b2B = b2[nt1 * 16 + lrow];
  const float bfv = (w < 2) ? bf[w * 16 + lrow] : 0.0f;

  for (int t = T_STEPS - 1; t >= 0; --t) {
    __syncthreads();   // posterior/A0/sc writes visible
    // L0: A0 (K=32) -> Q
    dense_layer<1, 0, true>(w0, HID, A0h, A0l, KPX, Qh, Ql, KPH, 0.f, 0.f,
                            sc, tfc + t * HID, nullptr, lrow, quad, nt0, nt1);
    __syncthreads();
    // L1: Q -> P
    dense_layer<8, 1, true>(w1, HID, Qh, Ql, KPH, Ph, Pl, KPH, b1A, b1B,
                            nullptr, nullptr, nullptr, lrow, quad, nt0, nt1);
    __syncthreads();
    // L2: P -> Q
    dense_layer<8, 1, true>(w2, HID, Ph, Pl, KPH, Qh, Ql, KPH, b2A, b2B,
                            nullptr, nullptr, nullptr, lrow, quad, nt0, nt1);
    __syncthreads();
    // Lf: Q -> eps (waves 0,1)
    if (w < 2) {
      dense_layer<8, 2, false>(wf, ADIM, Qh, Ql, KPH, nullptr, nullptr, 0, bfv, 0.f,
                               nullptr, nullptr, s_eps, lrow, quad, w, 0);
    }
    __syncthreads();
    // posterior + JAX noise; thread = (row r, dim d)
    {
      int r = tid >> 5, d = tid & 31;
      float sr  = coefs[0 * T_STEPS + t];
      float srm = coefs[1 * T_STEPS + t];
      float c1  = coefs[2 * T_STEPS + t];
      float c2  = coefs[3 * T_STEPS + t];
      float sig = (t != 0) ? coefs[4 * T_STEPS + t] : 0.0f;
      uint32_t k0 = keys[2 * t], k1 = keys[2 * t + 1];
      int grow = (r < 8) ? (base + r) : (2048 + base + r - 8);
      uint32_t jflat = (uint32_t)(grow * ADIM + d);
      float nz = bits_to_normal(random_bits32_partitionable(k0, k1, jflat));
      float xv = s_x[r * ADIM + d];
      float ev = s_eps[r * ADIM + d];
      float x0v = fminf(fmaxf(sr * xv - srm * ev, -1.0f), 1.0f);
      float xn = c1 * x0v + c2 * xv + sig * nz;
      s_x[r * ADIM + d] = xn;
      unsigned short h = f2bf(xn);
      A0h[r * KPX + d] = h; A0l[r * KPX + d] = f2bf(xn - bf2f(h));
    }
  }
  __syncthreads();
  {
    int r = tid >> 5, d = tid & 31;
    int grow = (r < 8) ? (base + r) : (2048 + base + r - 8);
    out[grow * ADIM + d] = fminf(fmaxf(s_x[r * ADIM + d], -1.0f), 1.0f);
  }
}

// ---------------- launcher ----------------
extern "C" void kernel_launch(void* const* d_in, const int* in_sizes, int n_in,
                              void* d_out, int out_size, void* d_ws, size_t ws_size,
                              hipStream_t stream) {
  const float* state = (const float*)d_in[0];
  const float* x_init = (const float*)d_in[1];
  const float* w_t1 = (const float*)d_in[2];
  const float* b_t1 = (const float*)d_in[3];
  const float* w_t2 = (const float*)d_in[4];
  const float* b_t2 = (const float*)d_in[5];
  const float* w0 = (const float*)d_in[6];
  const float* b0 = (const float*)d_in[7];
  const float* w1 = (const float*)d_in[8];
  const float* b1 = (const float*)d_in[9];
  const float* w2 = (const float*)d_in[10];
  const float* b2 = (const float*)d_in[11];
  const float* wf = (const float*)d_in[12];
  const float* bf = (const float*)d_in[13];
  float* out = (float*)d_out;

  // ws layout: tf_all[16000] f32 | coefs[5000] f32 | keys[2000] u32 | tfc[256000] f32
  float* tf_all = (float*)d_ws;
  float* coefs = tf_all + T_STEPS * TDIM;
  uint32_t* keys = (uint32_t*)(coefs + 5 * T_STEPS);
  float* tfc = (float*)(keys + 2 * T_STEPS);

  precompute_kernel<<<T_STEPS, 64, 0, stream>>>(w_t1, b_t1, w_t2, b_t2, tf_all, coefs, keys);
  tfc_kernel<<<T_STEPS, 256, 0, stream>>>(tf_all, w0, b0, tfc);
  diffusion_main<<<256, 512, 0, stream>>>(state, x_init, w0, b1, b2, bf, w1, w2, wf,
                                          tfc, coefs, keys, out);
}